// Round 6
// baseline (397.186 us; speedup 1.0000x reference)
//
#include <hip/hip_runtime.h>
#include <stdint.h>

#define T_ 128

typedef int v4i __attribute__((ext_vector_type(4)));

// ---------------------------------------------------------------------------
// prep 1: static B-fragments for mfma_i32_16x16x64_i8, biased i8 (byte-128).
// Fragment mf = (tau*5 + kappa)*2 + h. Lane l holds n = l&15,
// k-slots kin = (l>>4)*16 + 4r + b — identical slot->k map as scan's A, so
// any HW k-permutation cancels in the dot.
__global__ void prep_bfrag(const int* __restrict__ sc, uint4* __restrict__ bf) {
  int gid = blockIdx.x * 256 + threadIdx.x;
  if (gid >= 160 * 64) return;
  int mf = gid >> 6, l = gid & 63;
  int tau = mf / 10, rem = mf % 10;
  int kap = rem >> 1, h = rem & 1;
  int j = 16 * tau + (l & 15);
  int kinb = (l >> 4) * 16;
  unsigned wout[4];
#pragma unroll
  for (int r = 0; r < 4; ++r) {
    unsigned wrd = 0;
#pragma unroll
    for (int be = 0; be < 4; ++be) {
      int kin = kinb + 4 * r + be;
      int col = (kap == 0) ? kin : 64 + ((kap - 1) << 6) + kin;
      unsigned c = (unsigned)sc[j * 320 + col];
      unsigned byte = (h ? (c >> 8) : c) & 0xFFu;
      byte = (byte - 128u) & 0xFFu;
      wrd |= byte << (8 * be);
    }
    wout[r] = wrd;
  }
  bf[gid] = make_uint4(wout[0], wout[1], wout[2], wout[3]);
}

// prep 2: window bits packed to u64 per (b,t)
__global__ void prep_wbits(const int* __restrict__ bits,
                           unsigned long long* __restrict__ wb) {
  int gid = blockIdx.x * 256 + threadIdx.x;
  int wv = gid >> 6, lane = gid & 63;
  unsigned long long m = __ballot(bits[gid] != 0);
  if (lane == 0) wb[wv] = m;
}

// prep 3: bitpack (state_mem >= 0.5) -> 2 MiB table (L2-resident for scan)
__global__ void prep_bitpack(const float* __restrict__ sm,
                             unsigned long long* __restrict__ packed) {
  int base = blockIdx.x * (256 * 32) + threadIdx.x;
  int lane = threadIdx.x & 63;
#pragma unroll 1
  for (int it = 0; it < 32; ++it) {
    int idx = base + it * 256;
    float v = sm[idx];
    unsigned long long m = __ballot(v >= 0.5f);
    if (lane == 0) packed[idx >> 6] = m;
  }
}

// ---------------------------------------------------------------------------
// per-lane expand of a 16-bit slice into an i8 {0,1} A-fragment
static __device__ __forceinline__ v4i expand16(unsigned b16) {
  v4i a;
#pragma unroll
  for (int r = 0; r < 4; ++r) {
    unsigned nib = (b16 >> (4 * r)) & 0xFu;
    a[r] = (int)((nib * 0x00204081u) & 0x01010101u);
  }
  return a;
}

// scan + heads: 1 block per batch row, 16 waves of 64 -> 4 waves/SIMD for
// latency hiding of the recurrence chain. Wave w owns N-tile w
// (j in [16w,16w+16)), 10 MFMAs/step. Lanes 0..15 self-gather, ballot ->
// u16 -> msh; one barrier; all waves read 8 u32 state words. Heads on wave 0.
__global__ __launch_bounds__(1024, 4) void scan_heads(
    const uint4* __restrict__ bfrag,
    const unsigned long long* __restrict__ wbits,
    const unsigned* __restrict__ packed32,
    const int* __restrict__ head_conn,
    const int* __restrict__ head_coeffs,
    const float* __restrict__ head_mem,
    float* __restrict__ out) {
  __shared__ __align__(16) unsigned short msh16[2][16];
  const int tid = threadIdx.x;
  const int b = blockIdx.x;
  const int w = tid >> 6, l = tid & 63;
  const int qq = (l >> 4) & 3;          // 16-bit slice index within 64-bit chunk
  const int sh = 16 * (qq & 1);         // shift within a u32 state word
  const int wi = qq >> 1;               // u32 word parity within a u64 chunk

  // one-time: 10 static B-fragments (tile w) into registers (40 VGPRs)
  v4i bf[5][2];
#pragma unroll
  for (int k = 0; k < 5; ++k)
#pragma unroll
    for (int h = 0; h < 2; ++h) {
      int mf = (w * 5 + k) * 2 + h;
      bf[k][h] = __builtin_bit_cast(v4i, bfrag[mf * 64 + l]);
    }

  // fixed gather row for lanes 0..15: j = 16w + l
  const size_t rowbase = ((size_t)(16 * w + (l & 15)) << 11);

  unsigned words[8];
#pragma unroll
  for (int i = 0; i < 8; ++i) words[i] = 0u;  // state0 = 0
  unsigned long long wcur = wbits[b * 128];

  // pre-init accumulators with the t=0 window (k=0) contribution
  v4i acc0, acc1;
  {
    v4i aw = expand16((unsigned)((wcur >> (16 * qq)) & 0xFFFFu));
    v4i z = (v4i){0, 0, 0, 0};
    acc0 = __builtin_amdgcn_mfma_i32_16x16x64_i8(aw, bf[0][0], z, 0, 0, 0);
    acc1 = __builtin_amdgcn_mfma_i32_16x16x64_i8(aw, bf[0][1], z, 0, 0, 0);
  }

#pragma unroll 1
  for (int t = 0; t < T_; ++t) {
    // NB on the scalar pipe: state words are wave-uniform
    unsigned NB = (unsigned)__popcll(wcur);
#pragma unroll
    for (int i = 0; i < 8; ++i) {
      unsigned sw = (unsigned)__builtin_amdgcn_readfirstlane((int)words[i]);
      NB += (unsigned)__popc((int)sw);
    }

    // state-chunk A fragments and 8 MFMAs (k-chunks 1..4)
#pragma unroll
    for (int c = 0; c < 4; ++c) {
      v4i a = expand16((words[2 * c + wi] >> sh) & 0xFFFFu);
      acc0 = __builtin_amdgcn_mfma_i32_16x16x64_i8(a, bf[c + 1][0], acc0, 0, 0, 0);
      acc1 = __builtin_amdgcn_mfma_i32_16x16x64_i8(a, bf[c + 1][1], acc1, 0, 0, 0);
    }

    int tn = (t + 1 < T_) ? t + 1 : t;
    unsigned long long wnext = wbits[b * 128 + tn];

    // epilogue: addr for j = 16w + l (lanes 0..15); D rows are replicated, reg0
    unsigned corr = (NB * 32896u) & 0xFFFFu;  // 128*257 bias fixup
    unsigned ad = ((unsigned)acc0[0] + ((unsigned)acc1[0] << 8) + corr) & 0xFFFFu;

    // self-gather: 16 lanes/wave, 256 requests/block total
    unsigned bitv = 0;
    if (l < 16) {
      unsigned word = packed32[rowbase + (ad >> 5)];
      bitv = (word >> (ad & 31)) & 1u;
    }
    unsigned long long mq = __ballot(bitv != 0u);
    if (l == 0) msh16[t & 1][w] = (unsigned short)(mq & 0xFFFFu);

    // fill gather latency: next step's window-chunk MFMAs into fresh accs
    {
      v4i aw = expand16((unsigned)((wnext >> (16 * qq)) & 0xFFFFu));
      v4i z = (v4i){0, 0, 0, 0};
      acc0 = __builtin_amdgcn_mfma_i32_16x16x64_i8(aw, bf[0][0], z, 0, 0, 0);
      acc1 = __builtin_amdgcn_mfma_i32_16x16x64_i8(aw, bf[0][1], z, 0, 0, 0);
    }

    __syncthreads();

    uint4 u0 = ((const uint4*)&msh16[t & 1][0])[0];
    uint4 u1 = ((const uint4*)&msh16[t & 1][0])[1];
    words[0] = u0.x; words[1] = u0.y; words[2] = u0.z; words[3] = u0.w;
    words[4] = u1.x; words[5] = u1.y; words[6] = u1.z; words[7] = u1.w;
    wcur = wnext;
  }

  // ---- heads (wave 0): only the selected head per batch row
  if (w == 0) {
    int h = (int)((((wcur >> 61) & 1) << 2) | (((wcur >> 62) & 1) << 1) |
                  ((wcur >> 63) & 1));
    int ho = h * 64 + l;
    const int4* cn4 = (const int4*)(head_conn + ho * 8);
    const int4* cf4 = (const int4*)(head_coeffs + ho * 8);
    int4 cna = cn4[0], cnb = cn4[1];
    int4 cfa = cf4[0], cfb = cf4[1];
    int cns[8] = {cna.x, cna.y, cna.z, cna.w, cnb.x, cnb.y, cnb.z, cnb.w};
    int cfs[8] = {cfa.x, cfa.y, cfa.z, cfa.w, cfb.x, cfb.y, cfb.z, cfb.w};
    unsigned addr = 0;
#pragma unroll
    for (int k = 0; k < 8; ++k) {
      unsigned bit = (words[cns[k] >> 5] >> (cns[k] & 31)) & 1u;
      addr += bit * (unsigned)cfs[k];
    }
    addr &= 0xFFFFu;
    out[b * 64 + l] = head_mem[((size_t)ho << 16) + addr];
  }
}

extern "C" void kernel_launch(void* const* d_in, const int* in_sizes, int n_in,
                              void* d_out, int out_size, void* d_ws, size_t ws_size,
                              hipStream_t stream) {
  const int*   bits         = (const int*)d_in[0];
  const int*   state_coeffs = (const int*)d_in[1];
  const float* state_mem    = (const float*)d_in[2];
  const int*   head_conn    = (const int*)d_in[3];
  const int*   head_coeffs  = (const int*)d_in[4];
  const float* head_mem     = (const float*)d_in[5];
  float* out = (float*)d_out;

  char* ws = (char*)d_ws;
  uint4*              bfrag  = (uint4*)ws;                             // 160 KiB
  unsigned long long* wbits  = (unsigned long long*)(ws + (160 << 10)); // 128 KiB
  unsigned*           packed = (unsigned*)(ws + (288 << 10));          // 2 MiB

  prep_bfrag<<<40, 256, 0, stream>>>(state_coeffs, bfrag);
  prep_wbits<<<4096, 256, 0, stream>>>(bits, wbits);
  prep_bitpack<<<2048, 256, 0, stream>>>(state_mem, (unsigned long long*)packed);
  scan_heads<<<128, 1024, 0, stream>>>(bfrag, wbits, packed,
                                       head_conn, head_coeffs, head_mem, out);
}